// Round 1
// baseline (351.520 us; speedup 1.0000x reference)
//
#include <hip/hip_runtime.h>
#include <math.h>

// Problem constants (B,H,W,T,C) = (4,200,200,5,64), fp32 in/out.
constexpr int Bn = 4, Hn = 200, Wn = 200, Tn = 5, Cn = 64;
constexpr int C4 = Cn / 4;                       // 16 float4 per channel row
constexpr int TOTAL4 = Bn * Hn * Wn * Tn * C4;   // 12,800,000 float4 outputs
constexpr int BLOCK = 256;

__global__ __launch_bounds__(BLOCK) void tf_warp_kernel(
    const float4* __restrict__ in4,   // raw_bev_cache as float4
    const float*  __restrict__ ego,   // (B,3)
    float4*       __restrict__ out4)
{
    int idx = blockIdx.x * BLOCK + threadIdx.x;   // < TOTAL4 (exact grid)

    int c4   = idx & (C4 - 1);
    int rest = idx >> 4;          // pos*T + t
    int t    = rest % Tn;
    int pos  = rest / Tn;         // (b*H + h)*W + w
    int w    = pos % Wn;
    int bh   = pos / Wn;
    int h    = bh % Hn;
    int b    = bh / Hn;

    // note: linear float4 index of (b,h,w,t,c4) == idx itself.
    if (t == Tn - 1) {            // current frame: straight copy
        out4[idx] = in4[idx];
        return;
    }

    // --- per-(b,h,w) warp math (recomputed per thread; VALU is not the wall)
    float dxn  = ego[b * 3 + 0] / 100.0f;   // MAP_RANGE/2 = 100
    float dyn  = ego[b * 3 + 1] / 100.0f;
    float dyaw = ego[b * 3 + 2];
    float sth, cth;
    sincosf(dyaw, &sth, &cth);
    float tx = -(cth * dxn + sth * dyn);
    float ty =  sth * dxn - cth * dyn;

    float xs = (2.0f * (float)w + 1.0f) / (float)Wn - 1.0f;
    float ys = (2.0f * (float)h + 1.0f) / (float)Hn - 1.0f;

    float gx =  cth * xs + sth * ys + tx;
    float gy = -sth * xs + cth * ys + ty;

    float ix = ((gx + 1.0f) * (float)Wn - 1.0f) * 0.5f;
    float iy = ((gy + 1.0f) * (float)Hn - 1.0f) * 0.5f;

    float ix0f = floorf(ix), iy0f = floorf(iy);
    float wx1 = ix - ix0f, wx0 = 1.0f - wx1;
    float wy1 = iy - iy0f, wy0 = 1.0f - wy1;
    float ix1f = ix0f + 1.0f, iy1f = iy0f + 1.0f;

    bool vx0 = (ix0f >= 0.0f) && (ix0f <= (float)(Wn - 1));
    bool vx1 = (ix1f >= 0.0f) && (ix1f <= (float)(Wn - 1));
    bool vy0 = (iy0f >= 0.0f) && (iy0f <= (float)(Hn - 1));
    bool vy1 = (iy1f >= 0.0f) && (iy1f <= (float)(Hn - 1));

    int x0 = (int)fminf(fmaxf(ix0f, 0.0f), (float)(Wn - 1));
    int x1 = (int)fminf(fmaxf(ix1f, 0.0f), (float)(Wn - 1));
    int y0 = (int)fminf(fmaxf(iy0f, 0.0f), (float)(Hn - 1));
    int y1 = (int)fminf(fmaxf(iy1f, 0.0f), (float)(Hn - 1));

    // reference: gather with clipped index, then multiply by validity mask
    float w00 = wy0 * wx0 * ((vy0 && vx0) ? 1.0f : 0.0f);
    float w01 = wy0 * wx1 * ((vy0 && vx1) ? 1.0f : 0.0f);
    float w10 = wy1 * wx0 * ((vy1 && vx0) ? 1.0f : 0.0f);
    float w11 = wy1 * wx1 * ((vy1 && vx1) ? 1.0f : 0.0f);

    int bH = b * Hn;
    // float4 index of corner (y,x) at (t,c4): 16 consecutive lanes share (y,x),
    // so each corner load is a contiguous 256B segment -> coalesced dwordx4.
    int i00 = (((bH + y0) * Wn + x0) * Tn + t) * C4 + c4;
    int i01 = (((bH + y0) * Wn + x1) * Tn + t) * C4 + c4;
    int i10 = (((bH + y1) * Wn + x0) * Tn + t) * C4 + c4;
    int i11 = (((bH + y1) * Wn + x1) * Tn + t) * C4 + c4;

    float4 v00 = in4[i00];
    float4 v01 = in4[i01];
    float4 v10 = in4[i10];
    float4 v11 = in4[i11];

    float4 o;
    o.x = w00 * v00.x + w01 * v01.x + w10 * v10.x + w11 * v11.x;
    o.y = w00 * v00.y + w01 * v01.y + w10 * v10.y + w11 * v11.y;
    o.z = w00 * v00.z + w01 * v01.z + w10 * v10.z + w11 * v11.z;
    o.w = w00 * v00.w + w01 * v01.w + w10 * v10.w + w11 * v11.w;
    out4[idx] = o;
}

extern "C" void kernel_launch(void* const* d_in, const int* in_sizes, int n_in,
                              void* d_out, int out_size, void* d_ws, size_t ws_size,
                              hipStream_t stream) {
    const float4* in4 = (const float4*)d_in[0];   // raw_bev_cache fp32
    const float*  ego = (const float*)d_in[1];    // delta_ego_motion fp32 (4,3)
    float4* out4 = (float4*)d_out;

    int grid = TOTAL4 / BLOCK;                    // 50,000 blocks, exact
    tf_warp_kernel<<<grid, BLOCK, 0, stream>>>(in4, ego, out4);
}

// Round 2
// 342.045 us; speedup vs baseline: 1.0277x; 1.0277x over previous
//
#include <hip/hip_runtime.h>
#include <math.h>

// (B,H,W,T,C) = (4,200,200,5,64), fp32 in/out.
constexpr int Bn = 4, Hn = 200, Wn = 200, Tn = 5, Cn = 64;
constexpr int C4 = Cn / 4;                   // 16 float4 per (pixel,t)
constexpr int PIXELS = Bn * Hn * Wn;         // 160,000
constexpr int PPB = 16;                      // pixels per block
constexpr int BLOCK = PPB * C4;              // 256 threads
constexpr int PIX_STRIDE4 = Tn * C4;         // 80 float4 per pixel block

__global__ __launch_bounds__(BLOCK) void tf_warp_kernel(
    const float4* __restrict__ in4,
    const float*  __restrict__ ego,
    float4*       __restrict__ out4)
{
    __shared__ int   s_base[PPB][4];   // float4-index of corner (y,x) pixel block
    __shared__ float s_wgt[PPB][4];    // bilinear weights with validity folded

    const int tid  = threadIdx.x;
    const int pos0 = blockIdx.x * PPB;

    if (tid < PPB) {
        int pos = pos0 + tid;          // (b*H + h)*W + w
        int w   = pos % Wn;
        int bh  = pos / Wn;
        int h   = bh % Hn;
        int b   = bh / Hn;

        float dxn  = ego[b * 3 + 0] * 0.01f;   // / (MAP_RANGE/2 = 100)
        float dyn  = ego[b * 3 + 1] * 0.01f;
        float dyaw = ego[b * 3 + 2];
        float sth, cth;
        sincosf(dyaw, &sth, &cth);
        float tx = -(cth * dxn + sth * dyn);
        float ty =  sth * dxn - cth * dyn;

        float xs = (2.0f * (float)w + 1.0f) / (float)Wn - 1.0f;
        float ys = (2.0f * (float)h + 1.0f) / (float)Hn - 1.0f;

        float gx =  cth * xs + sth * ys + tx;
        float gy = -sth * xs + cth * ys + ty;

        float ix = ((gx + 1.0f) * (float)Wn - 1.0f) * 0.5f;
        float iy = ((gy + 1.0f) * (float)Hn - 1.0f) * 0.5f;

        float ix0f = floorf(ix), iy0f = floorf(iy);
        float wx1 = ix - ix0f, wx0 = 1.0f - wx1;
        float wy1 = iy - iy0f, wy0 = 1.0f - wy1;
        float ix1f = ix0f + 1.0f, iy1f = iy0f + 1.0f;

        bool vx0 = (ix0f >= 0.0f) && (ix0f <= (float)(Wn - 1));
        bool vx1 = (ix1f >= 0.0f) && (ix1f <= (float)(Wn - 1));
        bool vy0 = (iy0f >= 0.0f) && (iy0f <= (float)(Hn - 1));
        bool vy1 = (iy1f >= 0.0f) && (iy1f <= (float)(Hn - 1));

        int x0 = (int)fminf(fmaxf(ix0f, 0.0f), (float)(Wn - 1));
        int x1 = (int)fminf(fmaxf(ix1f, 0.0f), (float)(Wn - 1));
        int y0 = (int)fminf(fmaxf(iy0f, 0.0f), (float)(Hn - 1));
        int y1 = (int)fminf(fmaxf(iy1f, 0.0f), (float)(Hn - 1));

        int bH = b * Hn;
        s_base[tid][0] = ((bH + y0) * Wn + x0) * PIX_STRIDE4;
        s_base[tid][1] = ((bH + y0) * Wn + x1) * PIX_STRIDE4;
        s_base[tid][2] = ((bH + y1) * Wn + x0) * PIX_STRIDE4;
        s_base[tid][3] = ((bH + y1) * Wn + x1) * PIX_STRIDE4;
        s_wgt[tid][0]  = wy0 * wx0 * ((vy0 && vx0) ? 1.0f : 0.0f);
        s_wgt[tid][1]  = wy0 * wx1 * ((vy0 && vx1) ? 1.0f : 0.0f);
        s_wgt[tid][2]  = wy1 * wx0 * ((vy1 && vx0) ? 1.0f : 0.0f);
        s_wgt[tid][3]  = wy1 * wx1 * ((vy1 && vx1) ? 1.0f : 0.0f);
    }
    __syncthreads();

    const int p   = tid >> 4;          // local pixel 0..15
    const int c4  = tid & (C4 - 1);    // float4 lane within channel row
    const int pos = pos0 + p;
    const int obase = pos * PIX_STRIDE4 + c4;

    const int b00 = s_base[p][0] + c4;
    const int b01 = s_base[p][1] + c4;
    const int b10 = s_base[p][2] + c4;
    const int b11 = s_base[p][3] + c4;
    const float w00 = s_wgt[p][0];
    const float w01 = s_wgt[p][1];
    const float w10 = s_wgt[p][2];
    const float w11 = s_wgt[p][3];

    // Issue all 17 independent loads up front for max MLP.
    float4 v00[4], v01[4], v10[4], v11[4];
#pragma unroll
    for (int t = 0; t < 4; ++t) {
        v00[t] = in4[b00 + t * C4];
        v01[t] = in4[b01 + t * C4];
        v10[t] = in4[b10 + t * C4];
        v11[t] = in4[b11 + t * C4];
    }
    float4 cur = in4[obase + 4 * C4];  // current frame (t = T-1) copy

#pragma unroll
    for (int t = 0; t < 4; ++t) {
        float4 o;
        o.x = w00 * v00[t].x + w01 * v01[t].x + w10 * v10[t].x + w11 * v11[t].x;
        o.y = w00 * v00[t].y + w01 * v01[t].y + w10 * v10[t].y + w11 * v11[t].y;
        o.z = w00 * v00[t].z + w01 * v01[t].z + w10 * v10[t].z + w11 * v11[t].z;
        o.w = w00 * v00[t].w + w01 * v01[t].w + w10 * v10[t].w + w11 * v11[t].w;
        out4[obase + t * C4] = o;
    }
    out4[obase + 4 * C4] = cur;
}

extern "C" void kernel_launch(void* const* d_in, const int* in_sizes, int n_in,
                              void* d_out, int out_size, void* d_ws, size_t ws_size,
                              hipStream_t stream) {
    const float4* in4 = (const float4*)d_in[0];
    const float*  ego = (const float*)d_in[1];
    float4* out4 = (float4*)d_out;

    int grid = PIXELS / PPB;           // 10,000 blocks, exact
    tf_warp_kernel<<<grid, BLOCK, 0, stream>>>(in4, ego, out4);
}